// Round 2
// baseline (159.462 us; speedup 1.0000x reference)
//
#include <hip/hip_runtime.h>

// BinStats: per-channel searchsorted histogram.
//   x:(B=64, C=512, H=28, W=28) f32, bin_edges:(512,11), feature_ranges:(512,1),
//   bin_counts:(512,10). out[c][j] = bin_counts[c][j] + #{channel-c elems in bin j},
//   bin = searchsorted(inner_edges(9), x/range, side='left').
//
// R2 design notes:
//  - one block per channel (512 x 1024): edges wave-uniform (s_load), register
//    counters channel-pure, no global atomics.
//  - t[j] = #(x > e_j*r); hist[j] = t[j-1]-t[j] (edges sorted). 2 VALU/edge/elem
//    (v_cmp + v_addc) is the minimum for the general-edges formulation.
//  - NEW: 16 threads per batch-slab (64 slabs x 16 = 1024 threads) => zero
//    per-iteration address math: base computed once, 12 statically-unrolled
//    loads at offsets k*256B, plus predicated tail (196 = 12*16 + 4).
//  - launch_bounds(1024,2): 32 waves/CU needs <=64 VGPR; no big preload arrays.

#define N_CH   512
#define F4_PER_SLAB 196        // 784/4 floats per (b,c) slab, as float4
#define SLAB_STRIDE_F4 (N_CH * F4_PER_SLAB)   // float4 stride between batches
#define TOTAL_PER_CH (64 * 784)               // 50176

__global__ __launch_bounds__(1024, 2) void binstats_kernel(
    const float* __restrict__ x,
    const float* __restrict__ bin_edges,      // (512, 11)
    const float* __restrict__ feature_ranges, // (512,)
    const float* __restrict__ bin_counts,     // (512, 10)
    float* __restrict__ out)                  // (512, 10)
{
    const int c   = blockIdx.x;
    const int tid = threadIdx.x;
    const int b   = tid >> 4;     // batch slab 0..63
    const int sub = tid & 15;     // float4 lane within slab sweep

    __shared__ unsigned t_sh[9];
    if (tid < 9) t_sh[tid] = 0u;

    const float r = feature_ranges[c];
    float e[9];
#pragma unroll
    for (int j = 0; j < 9; ++j) e[j] = bin_edges[c * 11 + 1 + j] * r;

    __syncthreads();

    unsigned t[9];
#pragma unroll
    for (int j = 0; j < 9; ++j) t[j] = 0u;

    const float4* base = (const float4*)x
                       + (size_t)b * SLAB_STRIDE_F4 + c * F4_PER_SLAB + sub;

#pragma unroll
    for (int k = 0; k < 12; ++k) {
        const float4 v = base[k * 16];      // one base + static offset, no div
#pragma unroll
        for (int j = 0; j < 9; ++j) {
            t[j] += (unsigned)(v.x > e[j]);
            t[j] += (unsigned)(v.y > e[j]);
            t[j] += (unsigned)(v.z > e[j]);
            t[j] += (unsigned)(v.w > e[j]);
        }
    }
    if (sub < 4) {                           // tail: pos = sub + 192 < 196
        const float4 v = base[12 * 16];
#pragma unroll
        for (int j = 0; j < 9; ++j) {
            t[j] += (unsigned)(v.x > e[j]);
            t[j] += (unsigned)(v.y > e[j]);
            t[j] += (unsigned)(v.z > e[j]);
            t[j] += (unsigned)(v.w > e[j]);
        }
    }

    // Wave reduce (64 lanes) then one LDS atomic per wave per counter.
#pragma unroll
    for (int j = 0; j < 9; ++j) {
        unsigned v = t[j];
        for (int off = 32; off > 0; off >>= 1)
            v += __shfl_down(v, off, 64);
        if ((tid & 63) == 0) atomicAdd(&t_sh[j], v);
    }
    __syncthreads();

    // hist[0] = N - t[0]; hist[j] = t[j-1] - t[j]; hist[9] = t[8]
    if (tid < 10) {
        unsigned h;
        if (tid == 0)       h = (unsigned)TOTAL_PER_CH - t_sh[0];
        else if (tid == 9)  h = t_sh[8];
        else                h = t_sh[tid - 1] - t_sh[tid];
        out[c * 10 + tid] = bin_counts[c * 10 + tid] + (float)h;
    }
}

extern "C" void kernel_launch(void* const* d_in, const int* in_sizes, int n_in,
                              void* d_out, int out_size, void* d_ws, size_t ws_size,
                              hipStream_t stream) {
    const float* x  = (const float*)d_in[0];
    const float* be = (const float*)d_in[1];
    const float* fr = (const float*)d_in[2];
    const float* bc = (const float*)d_in[3];
    float* out = (float*)d_out;

    binstats_kernel<<<N_CH, 1024, 0, stream>>>(x, be, fr, bc, out);
}